// Round 1
// baseline (893.002 us; speedup 1.0000x reference)
//
#include <hip/hip_runtime.h>

// LSTM decoder: B=256, H=512, L=2, T=64, O=7
// Persistent kernel, round 8:
//  - flags/poll protocol REMOVED: data-embedded signaling. H0/H1 pre-filled
//    with 0xFF sentinel (0xFFFF is f16 NaN, never produced by finite math);
//    consumers validate each 16B chunk per-dword and retry with sc0sc1
//    bypass loads. Kills store-ack wait + flag-add + poll-detect roundtrips.
//  - __syncthreads() replaced by raw s_barrier + lgkmcnt(0) only: prefetch
//    loads and h-stores stay IN FLIGHT across barriers (counted vmcnt).
//  - h-store now two 8B system-scope atomic stores (compiler-visible: no
//    WAR hazard on store data regs, no explicit vmcnt(0) drain needed).
//  - FC fused into persistent-kernel tail (validated loads give ordering).

#define TT 64
#define NO 7

typedef _Float16 h16;
typedef __attribute__((ext_vector_type(8))) _Float16 half8;
typedef __attribute__((ext_vector_type(4))) float f32x4;
typedef __attribute__((ext_vector_type(4))) int i32x4;

__device__ __forceinline__ float sigf(float x)   { return 1.f / (1.f + __expf(-x)); }
__device__ __forceinline__ float tanhf_(float x) { return 1.f - 2.f / (__expf(2.f * x) + 1.f); }

// ---------------- prologue: pack [W_ih | W_hh] -> f16 Wc[l][n][k], k-major ----
__global__ __launch_bounds__(256) void prep_weights(
    const float* __restrict__ Wih, const float* __restrict__ Whh,
    h16* __restrict__ Wc)
{
    size_t gid = (size_t)blockIdx.x * 256 + threadIdx.x;
    size_t base = gid * 8;
    int l = (int)(base >> 21);
    int rem = (int)(base & ((1u << 21) - 1));
    int n = rem >> 10;
    int k = rem & 1023;
    const float* src = (k < 512)
        ? (Wih + ((size_t)l * 2048 + n) * 512 + k)
        : (Whh + ((size_t)l * 2048 + n) * 512 + (k - 512));
    const float4* s4 = (const float4*)src;
    float4 a = s4[0];
    float4 b = s4[1];
    half8 o;
    o[0] = (h16)a.x; o[1] = (h16)a.y; o[2] = (h16)a.z; o[3] = (h16)a.w;
    o[4] = (h16)b.x; o[5] = (h16)b.y; o[6] = (h16)b.z; o[7] = (h16)b.w;
    *(half8*)(Wc + base) = o;
}

// ---------------- prologue: init Xinit/H0init/H1init + bias ------------------
__global__ __launch_bounds__(256) void init_misc(
    const float* __restrict__ x, const float* __restrict__ h0,
    const float* __restrict__ bih, const float* __restrict__ bhh,
    h16* __restrict__ Xinit, h16* __restrict__ H0init, h16* __restrict__ H1init,
    float* __restrict__ bias)
{
    int i = blockIdx.x * 256 + threadIdx.x;
    if (i < 131072) { Xinit[i]  = (h16)x[i];           return; }
    i -= 131072;
    if (i < 131072) { H0init[i] = (h16)h0[i];          return; }
    i -= 131072;
    if (i < 131072) { H1init[i] = (h16)h0[131072 + i]; return; }
    i -= 131072;
    if (i < 4096) bias[i] = bih[i] + bhh[i];
}

// ---------------- persistent LSTM ------------------------------------------
// 256 WGs x 256 thr, 1 WG/CU. XCD-pinned: m = (wg&7)>>1, us = (wg>>3)+(wg&1)*32.
// WG: 64-row m-tile x 8 h-units. Wave w: rows (w>>1)*32..+32, units (w&1)*4..+4.
__global__ __launch_bounds__(256, 1) void lstm_persist(
    const h16* __restrict__ Wc, const float* __restrict__ bias,
    const float* __restrict__ c0in,
    const h16* __restrict__ Xinit, const h16* __restrict__ H0init,
    const h16* __restrict__ H1init,
    h16* __restrict__ H0, h16* __restrict__ H1,
    float* __restrict__ h_st, float* __restrict__ c_st,
    const float* __restrict__ Wfc, const float* __restrict__ bfc,
    float* __restrict__ out)
{
    __shared__ char ldsraw[65536];   // 2 x 32KB A-chunk double buffer

    const int wg   = blockIdx.x;
    const int m    = (wg & 7) >> 1;               // XCD-pinned m-group
    const int us   = (wg >> 3) + (wg & 1) * 32;   // unit slice 0..63
    const int tid  = threadIdx.x, w = tid >> 6, lane = tid & 63;
    const int u0   = us * 8;
    const int m0   = m * 64;
    const int rowbase = m0 + (w >> 1) * 32;
    const int ubase   = u0 + (w & 1) * 4;
    const int mcol = lane & 15, kq = lane >> 4;
    const int nrow = (mcol & 3) * 512 + ubase + (mcol >> 2);
    const int lrow = (w >> 1) * 32 + mcol;     // local row of m-subtile 0
    const int sw   = mcol & 7;                 // LDS XOR swizzle key
    const int lrloc = (w >> 1) * 32 + (lane >> 2);   // epilogue local row
    const int luloc = (w & 1) * 4 + (lane & 3);      // epilogue local unit

    // ---- B fragments for both layers -> registers/AGPRs (loaded once) ----
    half8 Bw0[32], Bw1[32];
#pragma unroll
    for (int ks = 0; ks < 32; ++ks) {
        Bw0[ks] = *(const half8*)(Wc + (size_t)nrow * 1024 + ks * 32 + kq * 8);
        Bw1[ks] = *(const half8*)(Wc + (size_t)(2048 + nrow) * 1024 + ks * 32 + kq * 8);
    }

    // ---- epilogue lane mapping (round-2/5/6 verified) ----
    const int eunit = ubase + (lane & 3);
    const int erow0 = rowbase + (lane >> 2);   // m-subtile 0; +16 for subtile 1
    float4 bz0 = make_float4(bias[eunit], bias[512 + eunit],
                             bias[1024 + eunit], bias[1536 + eunit]);
    float4 bz1 = make_float4(bias[2048 + eunit], bias[2048 + 512 + eunit],
                             bias[2048 + 1024 + eunit], bias[2048 + 1536 + eunit]);

    float creg[2][2], hreg[2][2];
#pragma unroll
    for (int mt = 0; mt < 2; ++mt) {
        creg[0][mt] = c0in[(erow0 + mt * 16) * 512 + eunit];
        creg[1][mt] = c0in[131072 + (erow0 + mt * 16) * 512 + eunit];
        hreg[0][mt] = 0.f; hreg[1][mt] = 0.f;
    }

// raw workgroup barrier: LDS ordering only — global loads/stores stay in
// flight across it (the whole point; __syncthreads would drain vmcnt(0)).
#define BARRIER() do {                                                        \
    asm volatile("s_waitcnt lgkmcnt(0)" ::: "memory");                        \
    __builtin_amdgcn_s_barrier();                                             \
    asm volatile("" ::: "memory");                                            \
} while (0)

// plain CACHED 16B loads of k-half `cs` (0/1) of the 64-row tile at BASE
// (row stride 1024B) into tmp[TB..TB+7]. Issue order defines vmcnt drains.
#define ISSUE_CHUNK(BASE, cs, TB) do {                                        \
    _Pragma("unroll")                                                         \
    for (int j = 0; j < 8; ++j) {                                             \
        int g = j * 256 + tid;                                                \
        int voff = (g >> 5) * 1024 + (cs) * 512 + (g & 31) * 16;              \
        asm volatile("global_load_dwordx4 %0, %1, %2"                         \
            : "=v"(tmp[(TB) + j]) : "v"(voff), "s"(BASE) : "memory");         \
    } } while (0)

// drain 8 loads (oldest-first), VALIDATE against 0xFF sentinel (per-dword;
// finite f16 pairs are never 0xFFFFFFFF), retry with sc0sc1 bypass loads,
// then write LDS buffer `par` with XOR swizzle. NB = outstanding-1 at entry
// (any not-yet-acked h-stores are OLDEST, so they only tighten the wait).
#define WRITE_CHUNK(par, TB, NB, BASE, cs) do {                               \
    _Pragma("unroll")                                                         \
    for (int j = 0; j < 8; ++j) {                                             \
        asm volatile("s_waitcnt vmcnt(%0)" :: "i"((NB) - j) : "memory");      \
        __builtin_amdgcn_sched_barrier(0);                                    \
        int g = j * 256 + tid;                                                \
        int row = g >> 5, bc = g & 31;                                        \
        int voff = row * 1024 + (cs) * 512 + bc * 16;                         \
        i32x4 v = tmp[(TB) + j];                                              \
        while (__builtin_expect((v[0] == -1) | (v[1] == -1) |                 \
                                (v[2] == -1) | (v[3] == -1), 0)) {            \
            asm volatile("global_load_dwordx4 %0, %1, %2 sc0 sc1\n\t"         \
                         "s_waitcnt vmcnt(0)"                                 \
                : "=v"(v) : "v"(voff), "s"(BASE) : "memory");                 \
        }                                                                     \
        *(i32x4*)(ldsraw + (par) * 32768 + row * 512 +                        \
                  ((bc ^ (row & 7)) * 16)) = v;                               \
    } } while (0)

// 8 k-steps of MFMA from LDS buffer `par` against B fragments BW[CO..CO+7]
#define MFMA_CHUNK(par, CO, BW) do {                                          \
    _Pragma("unroll")                                                         \
    for (int ks = 0; ks < 8; ++ks) {                                          \
        half8 a0 = *(const half8*)(ldsraw + (par) * 32768 + lrow * 512 +      \
                      (((kq + 4 * ks) ^ sw) * 16));                           \
        half8 a1 = *(const half8*)(ldsraw + (par) * 32768 +                   \
                      (lrow + 16) * 512 + (((kq + 4 * ks) ^ sw) * 16));       \
        acc0 = __builtin_amdgcn_mfma_f32_16x16x32_f16(a0, (BW)[(CO) + ks],    \
                                                      acc0, 0, 0, 0);         \
        acc1 = __builtin_amdgcn_mfma_f32_16x16x32_f16(a1, (BW)[(CO) + ks],    \
                                                      acc1, 0, 0, 0);         \
    } } while (0)

// chunk order: h0 (k512-767, BW[16..23]), h1 (k768-1023, BW[24..31]),
//              x0 (k0-255,   BW[0..7]),   x1 (k256-511,  BW[8..15])
// h-chunks are 2 phases old (validation ~never fires); x-chunks are 1 phase
// old — per-thread sentinel spin IS the synchronization.
#define PHASE(XSRC, HSRC, BW, BZ, CREG, HREG, HDST) do {                      \
    const char* bx = (const char*)(XSRC) + (size_t)m0 * 1024;                 \
    const char* bh = (const char*)(HSRC) + (size_t)m0 * 1024;                 \
    i32x4 tmp[16];                                                            \
    ISSUE_CHUNK(bh, 0, 0);                                                    \
    ISSUE_CHUNK(bh, 1, 8);                                                    \
    f32x4 acc0 = {0.f,0.f,0.f,0.f}, acc1 = {0.f,0.f,0.f,0.f};                 \
    WRITE_CHUNK(0, 0, 15, bh, 0);                                             \
    BARRIER();                                                                \
    ISSUE_CHUNK(bx, 0, 0);                                                    \
    MFMA_CHUNK(0, 16, BW);                                                    \
    WRITE_CHUNK(1, 8, 15, bh, 1);                                             \
    BARRIER();                                                                \
    ISSUE_CHUNK(bx, 1, 8);                                                    \
    MFMA_CHUNK(1, 24, BW);                                                    \
    WRITE_CHUNK(0, 0, 15, bx, 0);                                             \
    BARRIER();                                                                \
    MFMA_CHUNK(0, 0, BW);                                                     \
    WRITE_CHUNK(1, 8, 7, bx, 1);                                              \
    BARRIER();                                                                \
    MFMA_CHUNK(1, 8, BW);                                                     \
    /* ---- epilogue: transpose, cell, LDS-gather, coalesced 16B flush ---- */ \
    float* scrw = (float*)(ldsraw + w * 1024);                                \
    h16* hbuf = (h16*)(ldsraw + 8192);                                        \
    _Pragma("unroll")                                                         \
    for (int mt = 0; mt < 2; ++mt) {                                          \
        f32x4 accv = mt ? acc1 : acc0;                                        \
        _Pragma("unroll")                                                     \
        for (int rr = 0; rr < 4; ++rr)                                        \
            scrw[(kq * 4 + rr) * 16 + mcol] = accv[rr];                       \
        float4 g4 = *(const float4*)&scrw[(lane >> 2) * 16 + (lane & 3) * 4]; \
        float iv = sigf(g4.x + (BZ).x);                                       \
        float fv = sigf(g4.y + (BZ).y);                                       \
        float gv = tanhf_(g4.z + (BZ).z);                                     \
        float ov = sigf(g4.w + (BZ).w);                                       \
        float cc = fv * (CREG)[mt] + iv * gv;                                 \
        float hh = ov * tanhf_(cc);                                           \
        (CREG)[mt] = cc; (HREG)[mt] = hh;                                     \
        hbuf[(lrloc + mt * 16) * 8 + luloc] = (h16)hh;                        \
    }                                                                         \
    BARRIER();                                                                \
    if (tid < 64) {                                                           \
        const unsigned long long* hb =                                        \
            (const unsigned long long*)(ldsraw + 8192 + tid * 16);            \
        unsigned long long* dst = (unsigned long long*)                       \
            ((char*)(HDST) + (m0 + tid) * 1024 + u0 * 2);                     \
        unsigned long long lo = hb[0], hi = hb[1];                            \
        __hip_atomic_store(dst, lo, __ATOMIC_RELAXED,                         \
                           __HIP_MEMORY_SCOPE_SYSTEM);                        \
        __hip_atomic_store(dst + 1, hi, __ATOMIC_RELAXED,                     \
                           __HIP_MEMORY_SCOPE_SYSTEM);                        \
    }                                                                         \
    BARRIER();                                                                \
} while (0)

#pragma unroll 1
    for (int t = 0; t < TT; ++t) {
        const h16* x0src = t ? (H1 + (size_t)(t - 1) * 131072) : Xinit;
        const h16* h0src = t ? (H0 + (size_t)(t - 1) * 131072) : H0init;
        // layer 0: A = [x0src | h0src] -> H0[t]
        PHASE(x0src, h0src, Bw0, bz0, creg[0], hreg[0],
              (H0 + (size_t)t * 131072));
        const h16* h1src = t ? (H1 + (size_t)(t - 1) * 131072) : H1init;
        // layer 1: A = [H0[t] | h1src] -> H1[t]
        PHASE((H0 + (size_t)t * 131072), h1src, Bw1, bz1,
              creg[1], hreg[1], (H1 + (size_t)t * 131072));
    }

    // ---- final hT / cT (normal stores; kernel-end release flushes) ----
#pragma unroll
    for (int mt = 0; mt < 2; ++mt) {
        int idx = (erow0 + mt * 16) * 512 + eunit;
        h_st[idx]          = hreg[0][mt];
        h_st[131072 + idx] = hreg[1][mt];
        c_st[idx]          = creg[0][mt];
        c_st[131072 + idx] = creg[1][mt];
    }

    // ---- fused FC over all stored h1(t): (T*B) x 7, K=512 ----
    // WG handles 64 flat rows (row = t*256+b, t = wg>>2); validated loads
    // provide cross-WG ordering (stragglers' stores spin-waited per lane).
    {
        float* wl = (float*)ldsraw;
        for (int i = tid; i < NO * 512; i += 256) wl[i] = Wfc[i];
        __syncthreads();
        const int fcw = tid >> 6, fl = tid & 63;
#pragma unroll 1
        for (int rr = 0; rr < 16; ++rr) {
            const int row = wg * 64 + fcw * 16 + rr;
            const unsigned short* hr =
                (const unsigned short*)(H1 + (size_t)row * 512);
            float acc[NO] = {0.f, 0.f, 0.f, 0.f, 0.f, 0.f, 0.f};
#pragma unroll
            for (int i = 0; i < 8; ++i) {
                unsigned short hu = hr[i * 64 + fl];
                while (__builtin_expect(hu == 0xFFFFu, 0))
                    hu = __hip_atomic_load(hr + i * 64 + fl, __ATOMIC_RELAXED,
                                           __HIP_MEMORY_SCOPE_SYSTEM);
                float hv = (float)__builtin_bit_cast(h16, hu);
#pragma unroll
                for (int o = 0; o < NO; ++o)
                    acc[o] += hv * wl[o * 512 + i * 64 + fl];
            }
#pragma unroll
            for (int o = 0; o < NO; ++o)
#pragma unroll
                for (int off = 32; off; off >>= 1)
                    acc[o] += __shfl_down(acc[o], off);
            if (fl == 0) {
                const int t = row >> 8, b = row & 255;
#pragma unroll
                for (int o = 0; o < NO; ++o)
                    out[b * (TT * NO) + t * NO + o] = acc[o] + bfc[o];
            }
        }
    }
}

extern "C" void kernel_launch(void* const* d_in, const int* in_sizes, int n_in,
                              void* d_out, int out_size, void* d_ws, size_t ws_size,
                              hipStream_t stream)
{
    (void)in_sizes; (void)n_in; (void)out_size; (void)ws_size;
    const float* x   = (const float*)d_in[0];
    const float* h0  = (const float*)d_in[1];
    const float* c0  = (const float*)d_in[2];
    const float* Wih = (const float*)d_in[3];
    const float* Whh = (const float*)d_in[4];
    const float* bih = (const float*)d_in[5];
    const float* bhh = (const float*)d_in[6];
    const float* Wfc = (const float*)d_in[7];
    const float* bfc = (const float*)d_in[8];

    float* outf = (float*)d_out;                 // decoded (256*64*7)
    float* h_st = outf + 114688;                 // hT (2,256,512)
    float* c_st = h_st + 262144;                 // cT (2,256,512)

    char* ws = (char*)d_ws;
    h16*      Wc     = (h16*)ws;                         // 8 MB
    float*    bias   = (float*)(ws + 8388608);           // 16 KB
    h16*      Xinit  = (h16*)(ws + 8404992);             // 256 KB
    h16*      H0init = (h16*)(ws + 8667136);             // 256 KB
    h16*      H1init = (h16*)(ws + 8929280);             // 256 KB
    h16*      H0     = (h16*)(ws + 9191424);             // 16 MB (64 steps)
    h16*      H1     = (h16*)(ws + 25968640);            // 16 MB (64 steps)

    prep_weights<<<2048, 256, 0, stream>>>(Wih, Whh, Wc);
    init_misc<<<1552, 256, 0, stream>>>(x, h0, bih, bhh, Xinit, H0init, H1init, bias);
    // sentinel-fill H0|H1 (contiguous 32 MB): 0xFFFF f16 = NaN, never produced
    hipMemsetAsync(H0, 0xFF, 33554432, stream);
    lstm_persist<<<256, 256, 0, stream>>>(Wc, bias, c0, Xinit, H0init, H1init,
                                          H0, H1, h_st, c_st, Wfc, bfc, outf);
}